// Round 2
// baseline (9060.659 us; speedup 1.0000x reference)
//
#include <hip/hip_runtime.h>
#include <hip/hip_bf16.h>
#include <math.h>

// Problem constants
#define B_   32
#define NO_  512     // also ML
#define D_   1024
#define H_   16
#define DH_  64
#define D3_  3072

typedef __hip_bfloat16 bf16;

// ---------------------------------------------------------------------------
// Kernel 1: masked mean pooling.  grid(x = B*4, y = 2{v,t}), block 256.
// ---------------------------------------------------------------------------
__global__ __launch_bounds__(256) void pool_kernel(
    const float* __restrict__ v, const float* __restrict__ t,
    const float* __restrict__ vmask, const float* __restrict__ tmask,
    float* __restrict__ vmean, float* __restrict__ tmean) {
  const float* x; const float* m; float* out;
  if (blockIdx.y == 0) { x = v; m = vmask; out = vmean; }
  else                 { x = t; m = tmask; out = tmean; }
  int b = blockIdx.x >> 2;                       // 4 blocks per batch (1024/256)
  int d = ((blockIdx.x & 3) << 8) + threadIdx.x;
  float acc = 0.f, msum = 0.f;
  const float* xp = x + ((size_t)b * NO_) * D_ + d;
  const float* mp = m + b * NO_;
  for (int n = 0; n < NO_; ++n) {
    float mv = mp[n];
    acc  += xp[(size_t)n * D_] * mv;
    msum += mv;
  }
  out[b * D_ + d] = acc / msum;
}

// ---------------------------------------------------------------------------
// Kernel 2: gates = sigmoid(relu(mean) @ W + b).  grid(x = B*4, y = 2), 256.
// ---------------------------------------------------------------------------
__global__ __launch_bounds__(256) void gate_kernel(
    const float* __restrict__ vmean, const float* __restrict__ tmean,
    const float* __restrict__ Wv4t, const float* __restrict__ bv4t,
    const float* __restrict__ Wt4v, const float* __restrict__ bt4v,
    float* __restrict__ gv4t, float* __restrict__ gt4v) {
  const float* mean; const float* W; const float* bias; float* out;
  if (blockIdx.y == 0) { mean = vmean; W = Wv4t; bias = bv4t; out = gv4t; }
  else                 { mean = tmean; W = Wt4v; bias = bt4v; out = gt4v; }
  int b = blockIdx.x >> 2;
  int j = ((blockIdx.x & 3) << 8) + threadIdx.x;
  const float* mb = mean + b * D_;
  float acc = bias[j];
  for (int k = 0; k < D_; ++k) {
    float mv = mb[k]; mv = mv > 0.f ? mv : 0.f;
    acc += mv * W[(size_t)k * D_ + j];
  }
  out[b * D_ + j] = 1.f / (1.f + expf(-acc));
}

// ---------------------------------------------------------------------------
// Kernel 3a: KQV projection GEMM.
//   C_bf16[M,N] = ( relu(A[M,K]) @ W[K,N] + bias[N] ) * mask[row]
//   64x64 tile, 256 threads, 4x4 per thread, K-chunk 16, f32 accumulate.
// ---------------------------------------------------------------------------
__global__ __launch_bounds__(256) void gemm_kqv_kernel(
    const float* __restrict__ A, const float* __restrict__ W,
    const float* __restrict__ bias, const float* __restrict__ mask,
    bf16* __restrict__ C, int M, int N, int K) {
  __shared__ float As[16][65];   // [k][m]
  __shared__ float Bs[16][64];   // [k][n]
  int tid = threadIdx.x;
  int r = tid >> 4;              // 0..15
  int c = tid & 15;              // 0..15
  int rowBase = blockIdx.y * 64;
  int colBase = blockIdx.x * 64;
  float acc[4][4] = {};
  for (int k0 = 0; k0 < K; k0 += 16) {
    int idx = tid;
#pragma unroll
    for (int it = 0; it < 4; ++it) {
      int arow = idx >> 4, acol = idx & 15;
      float x = A[(size_t)(rowBase + arow) * K + k0 + acol];
      As[acol][arow] = x > 0.f ? x : 0.f;
      idx += 256;
    }
    idx = tid;
#pragma unroll
    for (int it = 0; it < 4; ++it) {
      int brow = idx >> 6, bcol = idx & 63;
      Bs[brow][bcol] = W[(size_t)(k0 + brow) * N + colBase + bcol];
      idx += 256;
    }
    __syncthreads();
#pragma unroll
    for (int kk = 0; kk < 16; ++kk) {
      float a[4], bv[4];
#pragma unroll
      for (int i = 0; i < 4; ++i) a[i] = As[kk][r * 4 + i];
#pragma unroll
      for (int j = 0; j < 4; ++j) bv[j] = Bs[kk][c + 16 * j];
#pragma unroll
      for (int i = 0; i < 4; ++i)
#pragma unroll
        for (int j = 0; j < 4; ++j)
          acc[i][j] += a[i] * bv[j];
    }
    __syncthreads();
  }
#pragma unroll
  for (int i = 0; i < 4; ++i) {
    int row = rowBase + r * 4 + i;
    float mk = mask[row];
#pragma unroll
    for (int j = 0; j < 4; ++j) {
      int col = colBase + c + 16 * j;
      C[(size_t)row * N + col] = __float2bfloat16((acc[i][j] + bias[col]) * mk);
    }
  }
}

// ---------------------------------------------------------------------------
// Kernel 3b: output projection GEMM.
//   C_f32[M,N] = ( A[M,K] + upd_bf16[M,K] ) @ W[K,N] + bias[N]
// ---------------------------------------------------------------------------
__global__ __launch_bounds__(256) void gemm_out_kernel(
    const float* __restrict__ A, const bf16* __restrict__ A2,
    const float* __restrict__ W, const float* __restrict__ bias,
    float* __restrict__ C, int M, int N, int K) {
  __shared__ float As[16][65];
  __shared__ float Bs[16][64];
  int tid = threadIdx.x;
  int r = tid >> 4;
  int c = tid & 15;
  int rowBase = blockIdx.y * 64;
  int colBase = blockIdx.x * 64;
  float acc[4][4] = {};
  for (int k0 = 0; k0 < K; k0 += 16) {
    int idx = tid;
#pragma unroll
    for (int it = 0; it < 4; ++it) {
      int arow = idx >> 4, acol = idx & 15;
      size_t gofs = (size_t)(rowBase + arow) * K + k0 + acol;
      As[acol][arow] = A[gofs] + __bfloat162float(A2[gofs]);
      idx += 256;
    }
    idx = tid;
#pragma unroll
    for (int it = 0; it < 4; ++it) {
      int brow = idx >> 6, bcol = idx & 63;
      Bs[brow][bcol] = W[(size_t)(k0 + brow) * N + colBase + bcol];
      idx += 256;
    }
    __syncthreads();
#pragma unroll
    for (int kk = 0; kk < 16; ++kk) {
      float a[4], bv[4];
#pragma unroll
      for (int i = 0; i < 4; ++i) a[i] = As[kk][r * 4 + i];
#pragma unroll
      for (int j = 0; j < 4; ++j) bv[j] = Bs[kk][c + 16 * j];
#pragma unroll
      for (int i = 0; i < 4; ++i)
#pragma unroll
        for (int j = 0; j < 4; ++j)
          acc[i][j] += a[i] * bv[j];
    }
    __syncthreads();
  }
#pragma unroll
  for (int i = 0; i < 4; ++i) {
    int row = rowBase + r * 4 + i;
#pragma unroll
    for (int j = 0; j < 4; ++j) {
      int col = colBase + c + 16 * j;
      C[(size_t)row * N + col] = acc[i][j] + bias[col];
    }
  }
}

// ---------------------------------------------------------------------------
// Kernel 4: attention for one modality.
//   trans (bf16): [B*512, 3072] = k|q|v fused rows (already masked+biased)
//   grid(x = 512/4, y = H, z = B), block 256 = 4 waves, one q-row per wave.
//   Gate folds into q: qs = q * (1+g)^2 / sqrt(dh).
// ---------------------------------------------------------------------------
__global__ __launch_bounds__(256) void attn_kernel(
    const bf16* __restrict__ trans, const float* __restrict__ mask,
    const float* __restrict__ gate, bf16* __restrict__ upd) {
  __shared__ float qs[4][64];
  __shared__ float attw[4][512];
  __shared__ float tile[64][65];
  int wave = threadIdx.x >> 6;
  int lane = threadIdx.x & 63;
  int b = blockIdx.z;
  int h = blockIdx.y;
  int q = blockIdx.x * 4 + wave;

  float g  = 1.f + gate[b * D_ + h * DH_ + lane];
  float qv = __bfloat162float(trans[((size_t)b * NO_ + q) * D3_ + D_ + h * DH_ + lane]);
  qs[wave][lane] = qv * g * g * 0.125f;   // 1/sqrt(64) = 0.125

  float s[8];
  float lmax = -INFINITY;
  for (int ch = 0; ch < 8; ++ch) {
    __syncthreads();
    for (int idx = threadIdx.x; idx < 64 * 64; idx += 256) {
      int kr = idx >> 6, kd = idx & 63;
      tile[kr][kd] = __bfloat162float(
          trans[((size_t)b * NO_ + ch * 64 + kr) * D3_ + h * DH_ + kd]);
    }
    __syncthreads();
    float acc = 0.f;
#pragma unroll 16
    for (int d = 0; d < 64; ++d)
      acc += qs[wave][d] * tile[lane][d];
    float mv = mask[b * NO_ + ch * 64 + lane];
    acc = (mv > 0.f) ? acc : -INFINITY;
    s[ch] = acc;
    lmax = fmaxf(lmax, acc);
  }
  for (int off = 32; off > 0; off >>= 1)
    lmax = fmaxf(lmax, __shfl_xor(lmax, off, 64));
  float lsum = 0.f;
#pragma unroll
  for (int ch = 0; ch < 8; ++ch) { s[ch] = expf(s[ch] - lmax); lsum += s[ch]; }
  for (int off = 32; off > 0; off >>= 1)
    lsum += __shfl_xor(lsum, off, 64);
  float inv = 1.f / lsum;
#pragma unroll
  for (int ch = 0; ch < 8; ++ch)
    attw[wave][ch * 64 + lane] = s[ch] * inv;

  float out = 0.f;
  for (int ch = 0; ch < 8; ++ch) {
    __syncthreads();
    for (int idx = threadIdx.x; idx < 64 * 64; idx += 256) {
      int kr = idx >> 6, kd = idx & 63;
      tile[kr][kd] = __bfloat162float(
          trans[((size_t)b * NO_ + ch * 64 + kr) * D3_ + 2 * D_ + h * DH_ + kd]);
    }
    __syncthreads();
#pragma unroll 16
    for (int kk = 0; kk < 64; ++kk)
      out += attw[wave][ch * 64 + kk] * tile[kk][lane];
  }
  upd[((size_t)b * NO_ + q) * D_ + h * DH_ + lane] = __float2bfloat16(out);
}

// ---------------------------------------------------------------------------
extern "C" void kernel_launch(void* const* d_in, const int* in_sizes, int n_in,
                              void* d_out, int out_size, void* d_ws, size_t ws_size,
                              hipStream_t stream) {
  const float* v      = (const float*)d_in[0];
  const float* t      = (const float*)d_in[1];
  const float* v_mask = (const float*)d_in[2];
  const float* t_mask = (const float*)d_in[3];
  const float* W_v4t  = (const float*)d_in[4];
  const float* b_v4t  = (const float*)d_in[5];
  const float* W_t4v  = (const float*)d_in[6];
  const float* b_t4v  = (const float*)d_in[7];
  const float* W_v    = (const float*)d_in[8];
  const float* b_v    = (const float*)d_in[9];
  const float* W_t    = (const float*)d_in[10];
  const float* b_t    = (const float*)d_in[11];
  const float* W_vo   = (const float*)d_in[12];
  const float* b_vo   = (const float*)d_in[13];
  const float* W_to   = (const float*)d_in[14];
  const float* b_to   = (const float*)d_in[15];
  float* out = (float*)d_out;

  const size_t M     = (size_t)B_ * NO_;    // 16384
  const size_t TRANS = M * D3_;             // 50,331,648 elems
  const size_t UPD   = M * D_;              // 16,777,216 elems

  // Workspace layout (total ~134.7 MB):
  //   f32: v_mean, t_mean, g_v4t, g_t4v   (4 * 32K floats = 512 KB)
  //   bf16: trans (100.7 MB, reused v then t), upd (33.6 MB, reused)
  float* ws     = (float*)d_ws;
  float* v_mean = ws;
  float* t_mean = v_mean + B_ * D_;
  float* g_v4t  = t_mean + B_ * D_;
  float* g_t4v  = g_v4t + B_ * D_;
  bf16*  trans  = (bf16*)(g_t4v + B_ * D_);
  bf16*  upd    = trans + TRANS;

  // 1. masked mean pooling
  pool_kernel<<<dim3(B_ * 4, 2), 256, 0, stream>>>(v, t, v_mask, t_mask, v_mean, t_mean);
  // 2. gates
  gate_kernel<<<dim3(B_ * 4, 2), 256, 0, stream>>>(v_mean, t_mean, W_v4t, b_v4t,
                                                   W_t4v, b_t4v, g_v4t, g_t4v);

  dim3 kqv_grid(D3_ / 64, M / 64);
  dim3 att_grid(NO_ / 4, H_, B_);
  dim3 out_grid(D_ / 64, M / 64);

  // ---- modality v (uses t4v gate) ----
  gemm_kqv_kernel<<<kqv_grid, 256, 0, stream>>>(v, W_v, b_v, v_mask, trans,
                                                (int)M, D3_, D_);
  attn_kernel<<<att_grid, 256, 0, stream>>>(trans, v_mask, g_t4v, upd);
  gemm_out_kernel<<<out_grid, 256, 0, stream>>>(v, upd, W_vo, b_vo, out,
                                                (int)M, D_, D_);

  // ---- modality t (uses v4t gate), reusing trans/upd ----
  gemm_kqv_kernel<<<kqv_grid, 256, 0, stream>>>(t, W_t, b_t, t_mask, trans,
                                                (int)M, D3_, D_);
  attn_kernel<<<att_grid, 256, 0, stream>>>(trans, t_mask, g_v4t, upd);
  gemm_out_kernel<<<out_grid, 256, 0, stream>>>(t, upd, W_to, b_to, out + UPD,
                                                (int)M, D_, D_);
}

// Round 4
// 4884.682 us; speedup vs baseline: 1.8549x; 1.8549x over previous
//
#include <hip/hip_runtime.h>
#include <hip/hip_bf16.h>
#include <math.h>

// Problem constants
#define B_   32
#define NO_  512     // also ML
#define D_   1024
#define H_   16
#define DH_  64
#define D3_  3072

typedef __hip_bfloat16 bf16;
typedef short short8 __attribute__((ext_vector_type(8)));
typedef float f32x4  __attribute__((ext_vector_type(4)));

__device__ inline short f2bf(float x) {
  bf16 h = __float2bfloat16(x);
  return *reinterpret_cast<short*>(&h);
}
__device__ inline float bf2f(short s) {
  union { unsigned int u; float f; } cv;
  cv.u = ((unsigned int)(unsigned short)s) << 16;
  return cv.f;
}

// ---------------------------------------------------------------------------
// Kernel 1: masked mean pooling.  grid(x = B*4, y = 2{v,t}), block 256.
// ---------------------------------------------------------------------------
__global__ __launch_bounds__(256) void pool_kernel(
    const float* __restrict__ v, const float* __restrict__ t,
    const float* __restrict__ vmask, const float* __restrict__ tmask,
    float* __restrict__ vmean, float* __restrict__ tmean) {
  const float* x; const float* m; float* out;
  if (blockIdx.y == 0) { x = v; m = vmask; out = vmean; }
  else                 { x = t; m = tmask; out = tmean; }
  int b = blockIdx.x >> 2;
  int d = ((blockIdx.x & 3) << 8) + threadIdx.x;
  float acc = 0.f, msum = 0.f;
  const float* xp = x + ((size_t)b * NO_) * D_ + d;
  const float* mp = m + b * NO_;
  for (int n = 0; n < NO_; ++n) {
    float mv = mp[n];
    acc  += xp[(size_t)n * D_] * mv;
    msum += mv;
  }
  out[b * D_ + d] = acc / msum;
}

// ---------------------------------------------------------------------------
// Kernel 2: gates = sigmoid(relu(mean) @ W + b).  grid(x = B*4, y = 2), 256.
// ---------------------------------------------------------------------------
__global__ __launch_bounds__(256) void gate_kernel(
    const float* __restrict__ vmean, const float* __restrict__ tmean,
    const float* __restrict__ Wv4t, const float* __restrict__ bv4t,
    const float* __restrict__ Wt4v, const float* __restrict__ bt4v,
    float* __restrict__ gv4t, float* __restrict__ gt4v) {
  const float* mean; const float* W; const float* bias; float* out;
  if (blockIdx.y == 0) { mean = vmean; W = Wv4t; bias = bv4t; out = gv4t; }
  else                 { mean = tmean; W = Wt4v; bias = bt4v; out = gt4v; }
  int b = blockIdx.x >> 2;
  int j = ((blockIdx.x & 3) << 8) + threadIdx.x;
  const float* mb = mean + b * D_;
  float acc = bias[j];
  for (int k = 0; k < D_; ++k) {
    float mv = mb[k]; mv = mv > 0.f ? mv : 0.f;
    acc += mv * W[(size_t)k * D_ + j];
  }
  out[b * D_ + j] = 1.f / (1.f + expf(-acc));
}

// ---------------------------------------------------------------------------
// Kernel 3a: KQV projection GEMM (f32 vector).
//   C_bf16[M,N] = ( relu(A[M,K]) @ W[K,N] + bias[N] ) * mask[row]
// ---------------------------------------------------------------------------
__global__ __launch_bounds__(256) void gemm_kqv_kernel(
    const float* __restrict__ A, const float* __restrict__ W,
    const float* __restrict__ bias, const float* __restrict__ mask,
    bf16* __restrict__ C, int M, int N, int K) {
  __shared__ float As[16][65];
  __shared__ float Bs[16][64];
  int tid = threadIdx.x;
  int r = tid >> 4;
  int c = tid & 15;
  int rowBase = blockIdx.y * 64;
  int colBase = blockIdx.x * 64;
  float acc[4][4] = {};
  for (int k0 = 0; k0 < K; k0 += 16) {
    int idx = tid;
#pragma unroll
    for (int it = 0; it < 4; ++it) {
      int arow = idx >> 4, acol = idx & 15;
      float x = A[(size_t)(rowBase + arow) * K + k0 + acol];
      As[acol][arow] = x > 0.f ? x : 0.f;
      idx += 256;
    }
    idx = tid;
#pragma unroll
    for (int it = 0; it < 4; ++it) {
      int brow = idx >> 6, bcol = idx & 63;
      Bs[brow][bcol] = W[(size_t)(k0 + brow) * N + colBase + bcol];
      idx += 256;
    }
    __syncthreads();
#pragma unroll
    for (int kk = 0; kk < 16; ++kk) {
      float a[4], bv[4];
#pragma unroll
      for (int i = 0; i < 4; ++i) a[i] = As[kk][r * 4 + i];
#pragma unroll
      for (int j = 0; j < 4; ++j) bv[j] = Bs[kk][c + 16 * j];
#pragma unroll
      for (int i = 0; i < 4; ++i)
#pragma unroll
        for (int j = 0; j < 4; ++j)
          acc[i][j] += a[i] * bv[j];
    }
    __syncthreads();
  }
#pragma unroll
  for (int i = 0; i < 4; ++i) {
    int row = rowBase + r * 4 + i;
    float mk = mask[row];
#pragma unroll
    for (int j = 0; j < 4; ++j) {
      int col = colBase + c + 16 * j;
      C[(size_t)row * N + col] = __float2bfloat16((acc[i][j] + bias[col]) * mk);
    }
  }
}

// ---------------------------------------------------------------------------
// Kernel 3b: output projection GEMM (f32 vector).
//   C_f32[M,N] = ( A[M,K] + upd_bf16[M,K] ) @ W[K,N] + bias[N]
// ---------------------------------------------------------------------------
__global__ __launch_bounds__(256) void gemm_out_kernel(
    const float* __restrict__ A, const bf16* __restrict__ A2,
    const float* __restrict__ W, const float* __restrict__ bias,
    float* __restrict__ C, int M, int N, int K) {
  __shared__ float As[16][65];
  __shared__ float Bs[16][64];
  int tid = threadIdx.x;
  int r = tid >> 4;
  int c = tid & 15;
  int rowBase = blockIdx.y * 64;
  int colBase = blockIdx.x * 64;
  float acc[4][4] = {};
  for (int k0 = 0; k0 < K; k0 += 16) {
    int idx = tid;
#pragma unroll
    for (int it = 0; it < 4; ++it) {
      int arow = idx >> 4, acol = idx & 15;
      size_t gofs = (size_t)(rowBase + arow) * K + k0 + acol;
      As[acol][arow] = A[gofs] + __bfloat162float(A2[gofs]);
      idx += 256;
    }
    idx = tid;
#pragma unroll
    for (int it = 0; it < 4; ++it) {
      int brow = idx >> 6, bcol = idx & 63;
      Bs[brow][bcol] = W[(size_t)(k0 + brow) * N + colBase + bcol];
      idx += 256;
    }
    __syncthreads();
#pragma unroll
    for (int kk = 0; kk < 16; ++kk) {
      float a[4], bv[4];
#pragma unroll
      for (int i = 0; i < 4; ++i) a[i] = As[kk][r * 4 + i];
#pragma unroll
      for (int j = 0; j < 4; ++j) bv[j] = Bs[kk][c + 16 * j];
#pragma unroll
      for (int i = 0; i < 4; ++i)
#pragma unroll
        for (int j = 0; j < 4; ++j)
          acc[i][j] += a[i] * bv[j];
    }
    __syncthreads();
  }
#pragma unroll
  for (int i = 0; i < 4; ++i) {
    int row = rowBase + r * 4 + i;
#pragma unroll
    for (int j = 0; j < 4; ++j) {
      int col = colBase + c + 16 * j;
      C[(size_t)row * N + col] = acc[i][j] + bias[col];
    }
  }
}

// ---------------------------------------------------------------------------
// Kernel 4: MFMA flash attention.
//   trans (bf16): [B*512, 3072] = k|q|v fused rows (masked+biased).
//   grid(x = NO/64, y = H, z = B), block 256 = 4 waves; wave w owns 16 q-rows.
//   16x16x32 bf16 MFMA; online softmax; gate folded into Q.
// ---------------------------------------------------------------------------
#define ATT_PAD 72

__global__ __launch_bounds__(256) void attn_mfma_kernel(
    const bf16* __restrict__ trans, const float* __restrict__ mask,
    const float* __restrict__ gate, bf16* __restrict__ upd) {
  __shared__ short Ks[64 * ATT_PAD];          // K chunk [key][dh]
  __shared__ short Vt[64 * ATT_PAD];          // V chunk transposed [dh][key]
  __shared__ short Ps[4][16 * ATT_PAD];       // per-wave P [q][key]

  const int tid  = threadIdx.x;
  const int wave = tid >> 6;
  const int lane = tid & 63;
  const int col  = lane & 15;                  // fragment col / m / n
  const int quad = lane >> 4;                  // 0..3
  const int b = blockIdx.z, h = blockIdx.y;
  const int qBase = blockIdx.x * 64 + wave * 16;

  const bf16* transB = trans + (size_t)b * NO_ * D3_;

  // ---- load Q fragments (A-layout: A[m=col][k=quad*8+j]), fold gate ----
  short8 qf[2];
  {
    const int q = qBase + col;
    const bf16* qp = transB + (size_t)q * D3_ + D_ + h * DH_;
    const float* gp = gate + b * D_ + h * DH_;
#pragma unroll
    for (int f = 0; f < 2; ++f) {
      const int dh0 = f * 32 + quad * 8;
      short8 raw = *(const short8*)(qp + dh0);
      short8 sc;
#pragma unroll
      for (int j = 0; j < 8; ++j) {
        float g = 1.f + gp[dh0 + j];
        sc[j] = f2bf(bf2f(raw[j]) * g * g * 0.125f);  // 1/sqrt(64)=0.125
      }
      qf[f] = sc;
    }
  }

  f32x4 O[4] = {{0,0,0,0},{0,0,0,0},{0,0,0,0},{0,0,0,0}};
  float m_i[4] = {-1e30f, -1e30f, -1e30f, -1e30f};
  float l_i[4] = {0.f, 0.f, 0.f, 0.f};

  const int key0 = tid >> 3;    // 0..31 (second half +32)
  const int mseg = tid & 7;     // dh segment 0..7 (8 bf16 each)

  for (int ch = 0; ch < 8; ++ch) {
    __syncthreads();   // previous chunk's readers done
    // ---- stage K [key][dh] and Vt [dh][key] (rotated-j writes) ----
#pragma unroll
    for (int half = 0; half < 2; ++half) {
      const int key = key0 + half * 32;
      const bf16* src = transB + (size_t)(ch * 64 + key) * D3_ + h * DH_ + mseg * 8;
      *(short8*)&Ks[key * ATT_PAD + mseg * 8] = *(const short8*)src;
      short8 vv = *(const short8*)(src + 2 * D_);        // V section (k|q|v)
#pragma unroll
      for (int i = 0; i < 8; ++i) {
        int j = (i + mseg) & 7;
        Vt[(mseg * 8 + j) * ATT_PAD + key] = vv[j];
      }
    }
    __syncthreads();

    // ---- S = Q K^T : 4 key-tiles x (2 MFMA over dh) ----
    f32x4 S[4];
#pragma unroll
    for (int f = 0; f < 4; ++f) {
      const int krow = (f * 16 + col) * ATT_PAD;
      short8 kb0 = *(short8*)&Ks[krow + quad * 8];
      short8 kb1 = *(short8*)&Ks[krow + 32 + quad * 8];
      f32x4 acc = {0.f, 0.f, 0.f, 0.f};
      acc = __builtin_amdgcn_mfma_f32_16x16x32_bf16(qf[0], kb0, acc, 0, 0, 0);
      acc = __builtin_amdgcn_mfma_f32_16x16x32_bf16(qf[1], kb1, acc, 0, 0, 0);
      S[f] = acc;
    }

    // ---- mask + online softmax (rows: quad*4+r, cols: col+16f) ----
    float mk[4];
#pragma unroll
    for (int f = 0; f < 4; ++f)
      mk[f] = mask[b * NO_ + ch * 64 + f * 16 + col];

#pragma unroll
    for (int r = 0; r < 4; ++r) {
      float sv[4];
      float mx = -1e30f;
#pragma unroll
      for (int f = 0; f < 4; ++f) {
        float s = S[f][r];
        s = (mk[f] > 0.f) ? s : -1e30f;
        sv[f] = s;
        mx = fmaxf(mx, s);
      }
#pragma unroll
      for (int off = 1; off < 16; off <<= 1)
        mx = fmaxf(mx, __shfl_xor(mx, off, 64));
      float mnew  = fmaxf(m_i[r], mx);
      float alpha = __expf(m_i[r] - mnew);
      float psum = 0.f;
#pragma unroll
      for (int f = 0; f < 4; ++f) {
        float p = __expf(sv[f] - mnew);
        psum += p;
        Ps[wave][(quad * 4 + r) * ATT_PAD + f * 16 + col] = f2bf(p);
      }
#pragma unroll
      for (int off = 1; off < 16; off <<= 1)
        psum += __shfl_xor(psum, off, 64);
      l_i[r] = l_i[r] * alpha + psum;
      m_i[r] = mnew;
#pragma unroll
      for (int t = 0; t < 4; ++t) O[t][r] *= alpha;
    }

    // ---- O += P V  (P: A-layout from per-wave LDS; V^T: B-layout) ----
#pragma unroll
    for (int k2 = 0; k2 < 2; ++k2) {
      short8 pa = *(short8*)&Ps[wave][col * ATT_PAD + k2 * 32 + quad * 8];
#pragma unroll
      for (int t = 0; t < 4; ++t) {
        short8 vb = *(short8*)&Vt[(t * 16 + col) * ATT_PAD + k2 * 32 + quad * 8];
        O[t] = __builtin_amdgcn_mfma_f32_16x16x32_bf16(pa, vb, O[t], 0, 0, 0);
      }
    }
  }

  // ---- epilogue: O /= l, store bf16 (C-layout) ----
#pragma unroll
  for (int t = 0; t < 4; ++t) {
#pragma unroll
    for (int r = 0; r < 4; ++r) {
      int q = qBase + quad * 4 + r;
      float o = O[t][r] / l_i[r];
      upd[((size_t)b * NO_ + q) * D_ + h * DH_ + t * 16 + col] = __float2bfloat16(o);
    }
  }
}

// ---------------------------------------------------------------------------
extern "C" void kernel_launch(void* const* d_in, const int* in_sizes, int n_in,
                              void* d_out, int out_size, void* d_ws, size_t ws_size,
                              hipStream_t stream) {
  const float* v      = (const float*)d_in[0];
  const float* t      = (const float*)d_in[1];
  const float* v_mask = (const float*)d_in[2];
  const float* t_mask = (const float*)d_in[3];
  const float* W_v4t  = (const float*)d_in[4];
  const float* b_v4t  = (const float*)d_in[5];
  const float* W_t4v  = (const float*)d_in[6];
  const float* b_t4v  = (const float*)d_in[7];
  const float* W_v    = (const float*)d_in[8];
  const float* b_v    = (const float*)d_in[9];
  const float* W_t    = (const float*)d_in[10];
  const float* b_t    = (const float*)d_in[11];
  const float* W_vo   = (const float*)d_in[12];
  const float* b_vo   = (const float*)d_in[13];
  const float* W_to   = (const float*)d_in[14];
  const float* b_to   = (const float*)d_in[15];
  float* out = (float*)d_out;

  const size_t M     = (size_t)B_ * NO_;    // 16384
  const size_t TRANS = M * D3_;             // 50,331,648 elems
  const size_t UPD   = M * D_;              // 16,777,216 elems

  // Workspace (~134.7 MB): f32 means/gates + bf16 trans/upd (reused v then t)
  float* ws     = (float*)d_ws;
  float* v_mean = ws;
  float* t_mean = v_mean + B_ * D_;
  float* g_v4t  = t_mean + B_ * D_;
  float* g_t4v  = g_v4t + B_ * D_;
  bf16*  trans  = (bf16*)(g_t4v + B_ * D_);
  bf16*  upd    = trans + TRANS;

  pool_kernel<<<dim3(B_ * 4, 2), 256, 0, stream>>>(v, t, v_mask, t_mask, v_mean, t_mean);
  gate_kernel<<<dim3(B_ * 4, 2), 256, 0, stream>>>(v_mean, t_mean, W_v4t, b_v4t,
                                                   W_t4v, b_t4v, g_v4t, g_t4v);

  dim3 kqv_grid(D3_ / 64, M / 64);
  dim3 att_grid(NO_ / 64, H_, B_);
  dim3 out_grid(D_ / 64, M / 64);

  // ---- modality v (uses t4v gate) ----
  gemm_kqv_kernel<<<kqv_grid, 256, 0, stream>>>(v, W_v, b_v, v_mask, trans,
                                                (int)M, D3_, D_);
  attn_mfma_kernel<<<att_grid, 256, 0, stream>>>(trans, v_mask, g_t4v, upd);
  gemm_out_kernel<<<out_grid, 256, 0, stream>>>(v, upd, W_vo, b_vo, out,
                                                (int)M, D_, D_);

  // ---- modality t (uses v4t gate) ----
  gemm_kqv_kernel<<<kqv_grid, 256, 0, stream>>>(t, W_t, b_t, t_mask, trans,
                                                (int)M, D3_, D_);
  attn_mfma_kernel<<<att_grid, 256, 0, stream>>>(trans, t_mask, g_v4t, upd);
  gemm_out_kernel<<<out_grid, 256, 0, stream>>>(t, upd, W_to, b_to, out + UPD,
                                                (int)M, D_, D_);
}

// Round 5
// 1032.983 us; speedup vs baseline: 8.7714x; 4.7287x over previous
//
#include <hip/hip_runtime.h>
#include <hip/hip_bf16.h>
#include <math.h>

// Problem constants
#define B_   32
#define NO_  512     // also ML
#define D_   1024
#define H_   16
#define DH_  64
#define D3_  3072

typedef __hip_bfloat16 bf16;
typedef short short8  __attribute__((ext_vector_type(8)));
typedef short short4v __attribute__((ext_vector_type(4)));
typedef float f32x4   __attribute__((ext_vector_type(4)));

__device__ inline short f2bf(float x) {
  bf16 h = __float2bfloat16(x);
  return *reinterpret_cast<short*>(&h);
}
__device__ inline float bf2f(short s) {
  union { unsigned int u; float f; } cv;
  cv.u = ((unsigned int)(unsigned short)s) << 16;
  return cv.f;
}

// async global->LDS, 16B per lane; LDS dest = wave-uniform base + lane*16
__device__ inline void gload_lds16(const void* g, void* l) {
  __builtin_amdgcn_global_load_lds(
      (__attribute__((address_space(1))) void*)(void*)(g),
      (__attribute__((address_space(3))) void*)(l), 16, 0, 0);
}

// ---------------------------------------------------------------------------
// Kernel 1: masked mean pooling.  grid(x = B*4, y = 2{v,t}), block 256.
// ---------------------------------------------------------------------------
__global__ __launch_bounds__(256) void pool_kernel(
    const float* __restrict__ v, const float* __restrict__ t,
    const float* __restrict__ vmask, const float* __restrict__ tmask,
    float* __restrict__ vmean, float* __restrict__ tmean) {
  const float* x; const float* m; float* out;
  if (blockIdx.y == 0) { x = v; m = vmask; out = vmean; }
  else                 { x = t; m = tmask; out = tmean; }
  int b = blockIdx.x >> 2;
  int d = ((blockIdx.x & 3) << 8) + threadIdx.x;
  float acc = 0.f, msum = 0.f;
  const float* xp = x + ((size_t)b * NO_) * D_ + d;
  const float* mp = m + b * NO_;
  for (int n = 0; n < NO_; ++n) {
    float mv = mp[n];
    acc  += xp[(size_t)n * D_] * mv;
    msum += mv;
  }
  out[b * D_ + d] = acc / msum;
}

// ---------------------------------------------------------------------------
// Kernel 2: gates = sigmoid(relu(mean) @ W + b).  grid(x = B*4, y = 2), 256.
// ---------------------------------------------------------------------------
__global__ __launch_bounds__(256) void gate_kernel(
    const float* __restrict__ vmean, const float* __restrict__ tmean,
    const float* __restrict__ Wv4t, const float* __restrict__ bv4t,
    const float* __restrict__ Wt4v, const float* __restrict__ bt4v,
    float* __restrict__ gv4t, float* __restrict__ gt4v) {
  const float* mean; const float* W; const float* bias; float* out;
  if (blockIdx.y == 0) { mean = vmean; W = Wv4t; bias = bv4t; out = gv4t; }
  else                 { mean = tmean; W = Wt4v; bias = bt4v; out = gt4v; }
  int b = blockIdx.x >> 2;
  int j = ((blockIdx.x & 3) << 8) + threadIdx.x;
  const float* mb = mean + b * D_;
  float acc = bias[j];
  for (int k = 0; k < D_; ++k) {
    float mv = mb[k]; mv = mv > 0.f ? mv : 0.f;
    acc += mv * W[(size_t)k * D_ + j];
  }
  out[b * D_ + j] = 1.f / (1.f + expf(-acc));
}

// ---------------------------------------------------------------------------
// Kernel P1: weight transpose+convert.  W[K][N] f32 -> Wt[N][K] bf16.
//   grid(N/32, K/32), block 256 (32x8).
// ---------------------------------------------------------------------------
__global__ __launch_bounds__(256) void wtrans_kernel(
    const float* __restrict__ W, short* __restrict__ Wt, int K, int N) {
  __shared__ float tile[32][33];
  int n0 = blockIdx.x * 32, k0 = blockIdx.y * 32;
  int tx = threadIdx.x & 31, ty = threadIdx.x >> 5;   // 32 x 8
#pragma unroll
  for (int i = 0; i < 4; ++i) {
    int kk = ty + i * 8;
    tile[kk][tx] = W[(size_t)(k0 + kk) * N + n0 + tx];
  }
  __syncthreads();
#pragma unroll
  for (int i = 0; i < 4; ++i) {
    int nn = ty + i * 8;
    Wt[(size_t)(n0 + nn) * K + k0 + tx] = f2bf(tile[tx][nn]);
  }
}

// ---------------------------------------------------------------------------
// Kernel P2: relu + f32->bf16 convert (KQV GEMM input).
// ---------------------------------------------------------------------------
__global__ __launch_bounds__(256) void reluconv_kernel(
    const float* __restrict__ x, short* __restrict__ y) {
  int i = (blockIdx.x * 256 + threadIdx.x) * 4;
  float4 vv = *(const float4*)(x + i);
  short4v o;
  o[0] = f2bf(vv.x > 0.f ? vv.x : 0.f);
  o[1] = f2bf(vv.y > 0.f ? vv.y : 0.f);
  o[2] = f2bf(vv.z > 0.f ? vv.z : 0.f);
  o[3] = f2bf(vv.w > 0.f ? vv.w : 0.f);
  *(short4v*)(y + i) = o;
}

// ---------------------------------------------------------------------------
// Kernel 3: bf16 MFMA GEMM (m97 structure).
//   C[M][N] = A[M][K] @ Wt[N][K]^T  (+bias, then per-EPI post-op)
//   EPI 0: bf16 store, val = (acc+bias)*mask[row]   (KQV projection)
//   EPI 1: f32 store,  val = acc+bias               (output projection)
//   128x128 tile, BK=32, 4 waves (2x2 of 64x64), global_load_lds staging.
// ---------------------------------------------------------------------------
template<int EPI>
__global__ __launch_bounds__(256) void mfma_gemm_kernel(
    const short* __restrict__ A, const short* __restrict__ Bt,
    const float* __restrict__ bias, const float* __restrict__ mask,
    void* __restrict__ Cout, int M, int N, int K) {
  __shared__ short As[128 * 32];   // [m][kk], contiguous (global_load_lds order)
  __shared__ short Bs[128 * 32];   // [n][kk]
  const int tid  = threadIdx.x;
  const int wave = tid >> 6, lane = tid & 63;
  const int col  = lane & 15, quad = lane >> 4;
  const int wm   = wave >> 1, wn = wave & 1;
  const int rowBase = blockIdx.y * 128;
  const int colBase = blockIdx.x * 128;

  f32x4 zero = {0.f, 0.f, 0.f, 0.f};
  f32x4 acc[4][4];
#pragma unroll
  for (int i = 0; i < 4; ++i)
#pragma unroll
    for (int j = 0; j < 4; ++j) acc[i][j] = zero;

  // staging: wave w covers rows [w*32, w*32+32) of both As and Bs.
  // lane L -> row w*32 + (inst*16) + L/4, k-seg (L&3)*8  (16 B each)
  const int lrow = lane >> 2;
  const int lseg = (lane & 3) * 8;
  const short* gA0 = A  + (size_t)(rowBase + wave * 32 + lrow) * K + lseg;
  const short* gA1 = gA0 + (size_t)16 * K;
  const short* gB0 = Bt + (size_t)(colBase + wave * 32 + lrow) * K + lseg;
  const short* gB1 = gB0 + (size_t)16 * K;
  short* lA0 = As + (wave * 32) * 32;
  short* lA1 = As + (wave * 32 + 16) * 32;
  short* lB0 = Bs + (wave * 32) * 32;
  short* lB1 = Bs + (wave * 32 + 16) * 32;

  for (int k0 = 0; k0 < K; k0 += 32) {
    __syncthreads();                 // previous iter's LDS readers done
    gload_lds16(gA0 + k0, lA0);
    gload_lds16(gA1 + k0, lA1);
    gload_lds16(gB0 + k0, lB0);
    gload_lds16(gB1 + k0, lB1);
    __syncthreads();                 // drains vmcnt before barrier
    short8 af[4], bfr[4];
#pragma unroll
    for (int i = 0; i < 4; ++i)
      af[i] = *(short8*)&As[(wm * 64 + i * 16 + col) * 32 + quad * 8];
#pragma unroll
    for (int j = 0; j < 4; ++j)
      bfr[j] = *(short8*)&Bs[(wn * 64 + j * 16 + col) * 32 + quad * 8];
#pragma unroll
    for (int i = 0; i < 4; ++i)
#pragma unroll
      for (int j = 0; j < 4; ++j)
        acc[i][j] = __builtin_amdgcn_mfma_f32_16x16x32_bf16(af[i], bfr[j],
                                                            acc[i][j], 0, 0, 0);
  }

  // epilogue: C-layout row = quad*4+r, col = lane&15 per 16x16 tile
#pragma unroll
  for (int i = 0; i < 4; ++i) {
    const int row = rowBase + wm * 64 + i * 16 + quad * 4;
    float mk[4];
    if (EPI == 0) {
#pragma unroll
      for (int r = 0; r < 4; ++r) mk[r] = mask[row + r];
    }
#pragma unroll
    for (int j = 0; j < 4; ++j) {
      const int c = colBase + wn * 64 + j * 16 + col;
      const float bv = bias[c];
#pragma unroll
      for (int r = 0; r < 4; ++r) {
        float val = acc[i][j][r] + bv;
        if (EPI == 0) {
          val *= mk[r];
          ((short*)Cout)[(size_t)(row + r) * N + c] = f2bf(val);
        } else {
          ((float*)Cout)[(size_t)(row + r) * N + c] = val;
        }
      }
    }
  }
}

// ---------------------------------------------------------------------------
// Kernel 4: MFMA flash attention.  Epilogue fused: a2 = bf16(x + O/l).
//   trans (bf16 as short): [B*512, 3072] = k|q|v rows (masked+biased).
//   grid(x = NO/64, y = H, z = B), block 256 = 4 waves; wave owns 16 q-rows.
// ---------------------------------------------------------------------------
#define ATT_PAD 72

__global__ __launch_bounds__(256) void attn_mfma_kernel(
    const short* __restrict__ trans, const float* __restrict__ mask,
    const float* __restrict__ gate, const float* __restrict__ x,
    short* __restrict__ a2) {
  __shared__ short Ks[64 * ATT_PAD];          // K chunk [key][dh]
  __shared__ short Vt[64 * ATT_PAD];          // V chunk transposed [dh][key]
  __shared__ short Ps[4][16 * ATT_PAD];       // per-wave P [q][key]

  const int tid  = threadIdx.x;
  const int wave = tid >> 6;
  const int lane = tid & 63;
  const int col  = lane & 15;
  const int quad = lane >> 4;
  const int b = blockIdx.z, h = blockIdx.y;
  const int qBase = blockIdx.x * 64 + wave * 16;

  const short* transB = trans + (size_t)b * NO_ * D3_;

  // Q fragments (A-layout), gate folded: q * (1+g)^2 / 8
  short8 qf[2];
  {
    const int q = qBase + col;
    const short* qp = transB + (size_t)q * D3_ + D_ + h * DH_;
    const float* gp = gate + b * D_ + h * DH_;
#pragma unroll
    for (int f = 0; f < 2; ++f) {
      const int dh0 = f * 32 + quad * 8;
      short8 raw = *(const short8*)(qp + dh0);
      short8 sc;
#pragma unroll
      for (int j = 0; j < 8; ++j) {
        float g = 1.f + gp[dh0 + j];
        sc[j] = f2bf(bf2f(raw[j]) * g * g * 0.125f);
      }
      qf[f] = sc;
    }
  }

  f32x4 O[4] = {{0,0,0,0},{0,0,0,0},{0,0,0,0},{0,0,0,0}};
  float m_i[4] = {-1e30f, -1e30f, -1e30f, -1e30f};
  float l_i[4] = {0.f, 0.f, 0.f, 0.f};

  const int key0 = tid >> 3;
  const int mseg = tid & 7;

  for (int ch = 0; ch < 8; ++ch) {
    __syncthreads();
#pragma unroll
    for (int half = 0; half < 2; ++half) {
      const int key = key0 + half * 32;
      const short* src = transB + (size_t)(ch * 64 + key) * D3_ + h * DH_ + mseg * 8;
      *(short8*)&Ks[key * ATT_PAD + mseg * 8] = *(const short8*)src;
      short8 vv = *(const short8*)(src + 2 * D_);        // V section
#pragma unroll
      for (int i = 0; i < 8; ++i) {
        int j = (i + mseg) & 7;
        Vt[(mseg * 8 + j) * ATT_PAD + key] = vv[j];
      }
    }
    __syncthreads();

    // S = Q K^T
    f32x4 S[4];
#pragma unroll
    for (int f = 0; f < 4; ++f) {
      const int krow = (f * 16 + col) * ATT_PAD;
      short8 kb0 = *(short8*)&Ks[krow + quad * 8];
      short8 kb1 = *(short8*)&Ks[krow + 32 + quad * 8];
      f32x4 acc = {0.f, 0.f, 0.f, 0.f};
      acc = __builtin_amdgcn_mfma_f32_16x16x32_bf16(qf[0], kb0, acc, 0, 0, 0);
      acc = __builtin_amdgcn_mfma_f32_16x16x32_bf16(qf[1], kb1, acc, 0, 0, 0);
      S[f] = acc;
    }

    float mk[4];
#pragma unroll
    for (int f = 0; f < 4; ++f)
      mk[f] = mask[b * NO_ + ch * 64 + f * 16 + col];

#pragma unroll
    for (int r = 0; r < 4; ++r) {
      float sv[4];
      float mx = -1e30f;
#pragma unroll
      for (int f = 0; f < 4; ++f) {
        float s = S[f][r];
        s = (mk[f] > 0.f) ? s : -1e30f;
        sv[f] = s;
        mx = fmaxf(mx, s);
      }
#pragma unroll
      for (int off = 1; off < 16; off <<= 1)
        mx = fmaxf(mx, __shfl_xor(mx, off, 64));
      float mnew  = fmaxf(m_i[r], mx);
      float alpha = __expf(m_i[r] - mnew);
      float psum = 0.f;
#pragma unroll
      for (int f = 0; f < 4; ++f) {
        float p = __expf(sv[f] - mnew);
        psum += p;
        Ps[wave][(quad * 4 + r) * ATT_PAD + f * 16 + col] = f2bf(p);
      }
#pragma unroll
      for (int off = 1; off < 16; off <<= 1)
        psum += __shfl_xor(psum, off, 64);
      l_i[r] = l_i[r] * alpha + psum;
      m_i[r] = mnew;
#pragma unroll
      for (int t = 0; t < 4; ++t) O[t][r] *= alpha;
    }

    // O += P V
#pragma unroll
    for (int k2 = 0; k2 < 2; ++k2) {
      short8 pa = *(short8*)&Ps[wave][col * ATT_PAD + k2 * 32 + quad * 8];
#pragma unroll
      for (int t = 0; t < 4; ++t) {
        short8 vb = *(short8*)&Vt[(t * 16 + col) * ATT_PAD + k2 * 32 + quad * 8];
        O[t] = __builtin_amdgcn_mfma_f32_16x16x32_bf16(pa, vb, O[t], 0, 0, 0);
      }
    }
  }

  // epilogue: a2 = bf16( x + O/l )
#pragma unroll
  for (int t = 0; t < 4; ++t) {
#pragma unroll
    for (int r = 0; r < 4; ++r) {
      int q = qBase + quad * 4 + r;
      size_t idx = ((size_t)b * NO_ + q) * D_ + h * DH_ + t * 16 + col;
      a2[idx] = f2bf(x[idx] + O[t][r] / l_i[r]);
    }
  }
}

// ---------------------------------------------------------------------------
extern "C" void kernel_launch(void* const* d_in, const int* in_sizes, int n_in,
                              void* d_out, int out_size, void* d_ws, size_t ws_size,
                              hipStream_t stream) {
  const float* v      = (const float*)d_in[0];
  const float* t      = (const float*)d_in[1];
  const float* v_mask = (const float*)d_in[2];
  const float* t_mask = (const float*)d_in[3];
  const float* W_v4t  = (const float*)d_in[4];
  const float* b_v4t  = (const float*)d_in[5];
  const float* W_t4v  = (const float*)d_in[6];
  const float* b_t4v  = (const float*)d_in[7];
  const float* W_v    = (const float*)d_in[8];
  const float* b_v    = (const float*)d_in[9];
  const float* W_t    = (const float*)d_in[10];
  const float* b_t    = (const float*)d_in[11];
  const float* W_vo   = (const float*)d_in[12];
  const float* b_vo   = (const float*)d_in[13];
  const float* W_to   = (const float*)d_in[14];
  const float* b_to   = (const float*)d_in[15];
  float* out = (float*)d_out;

  const size_t M = (size_t)B_ * NO_;           // 16384

  // Workspace (~151.5 MB):
  float* ws     = (float*)d_ws;
  float* v_mean = ws;
  float* t_mean = v_mean + B_ * D_;
  float* g_v4t  = t_mean + B_ * D_;
  float* g_t4v  = g_v4t + B_ * D_;
  short* trans  = (short*)(g_t4v + B_ * D_);   // M*3072 bf16
  short* Abf    = trans + M * D3_;             // M*1024 bf16 (relu-in, then x+upd)
  short* Wt_v   = Abf + M * D_;                // 3072*1024 bf16
  short* Wt_t   = Wt_v + (size_t)D3_ * D_;
  short* Wt_vo  = Wt_t + (size_t)D3_ * D_;     // 1024*1024 bf16
  short* Wt_to  = Wt_vo + (size_t)D_ * D_;

  pool_kernel<<<dim3(B_ * 4, 2), 256, 0, stream>>>(v, t, v_mask, t_mask, v_mean, t_mean);
  gate_kernel<<<dim3(B_ * 4, 2), 256, 0, stream>>>(v_mean, t_mean, W_v4t, b_v4t,
                                                   W_t4v, b_t4v, g_v4t, g_t4v);

  // weight prep: W[K][N] f32 -> Wt[N][K] bf16
  wtrans_kernel<<<dim3(D3_ / 32, D_ / 32), 256, 0, stream>>>(W_v,  Wt_v,  D_, D3_);
  wtrans_kernel<<<dim3(D3_ / 32, D_ / 32), 256, 0, stream>>>(W_t,  Wt_t,  D_, D3_);
  wtrans_kernel<<<dim3(D_ / 32,  D_ / 32), 256, 0, stream>>>(W_vo, Wt_vo, D_, D_);
  wtrans_kernel<<<dim3(D_ / 32,  D_ / 32), 256, 0, stream>>>(W_to, Wt_to, D_, D_);

  dim3 kqv_grid(D3_ / 128, M / 128);   // 24 x 128
  dim3 out_grid(D_ / 128,  M / 128);   // 8 x 128
  dim3 att_grid(NO_ / 64, H_, B_);
  int  conv_blocks = (int)(M * D_ / (256 * 4));

  // ---- modality v (uses t4v gate) ----
  reluconv_kernel<<<conv_blocks, 256, 0, stream>>>(v, Abf);
  mfma_gemm_kernel<0><<<kqv_grid, 256, 0, stream>>>(Abf, Wt_v, b_v, v_mask,
                                                    trans, (int)M, D3_, D_);
  attn_mfma_kernel<<<att_grid, 256, 0, stream>>>(trans, v_mask, g_t4v, v, Abf);
  mfma_gemm_kernel<1><<<out_grid, 256, 0, stream>>>(Abf, Wt_vo, b_vo, nullptr,
                                                    out, (int)M, D_, D_);

  // ---- modality t (uses v4t gate) ----
  reluconv_kernel<<<conv_blocks, 256, 0, stream>>>(t, Abf);
  mfma_gemm_kernel<0><<<kqv_grid, 256, 0, stream>>>(Abf, Wt_t, b_t, t_mask,
                                                    trans, (int)M, D3_, D_);
  attn_mfma_kernel<<<att_grid, 256, 0, stream>>>(trans, t_mask, g_v4t, t, Abf);
  mfma_gemm_kernel<1><<<out_grid, 256, 0, stream>>>(Abf, Wt_to, b_to, nullptr,
                                                    out + M * D_, (int)M, D_, D_);
}